// Round 1
// baseline (1630.005 us; speedup 1.0000x reference)
//
#include <hip/hip_runtime.h>
#include <hip/hip_bf16.h>
#include <math.h>

#define B_  2
#define N_  2048
#define D_  1024
#define H_  16
#define HD_ 64
#define TD_ 3072   // 3*D

// ---------------------------------------------------------------------------
// NT GEMM: C[M,Ncol] = A[M,K] @ W[Ncol,K]^T + bias, f32.
// mode 0: plain.  mode 1: qkv epilogue (q *= 0.125; v *= gate(n) for n<n_ctx)
// 64x64 tile, BK=16, 256 threads, 4x4 per thread.
// ---------------------------------------------------------------------------
__global__ __launch_bounds__(256) void gemm_nt_kernel(
    const float* __restrict__ A,
    const float* __restrict__ W,
    const float* __restrict__ bias,
    float* __restrict__ C,
    int M, int Ncol, int K, int mode,
    const float* __restrict__ ctx_trust,
    const float* __restrict__ trust_scale,
    const int* __restrict__ n_ctx_p)
{
    __shared__ __align__(16) float As[16][68];
    __shared__ __align__(16) float Bs[16][68];
    const int tid = threadIdx.x;
    const int lr = tid >> 2;          // 0..63 tile row/col for staging
    const int lc = (tid & 3) << 2;    // k offset 0,4,8,12
    const int ty = tid >> 4;          // 0..15 output row group
    const int tx = tid & 15;          // 0..15 output col group
    const int row0 = blockIdx.y << 6;
    const int col0 = blockIdx.x << 6;
    const float* Ap = A + (size_t)(row0 + lr) * K + lc;
    const float* Wp = W + (size_t)(col0 + lr) * K + lc;
    float acc[4][4] = {};
    for (int k0 = 0; k0 < K; k0 += 16) {
        const float4 a4 = *(const float4*)(Ap + k0);
        const float4 b4 = *(const float4*)(Wp + k0);
        __syncthreads();
        As[lc+0][lr] = a4.x; As[lc+1][lr] = a4.y; As[lc+2][lr] = a4.z; As[lc+3][lr] = a4.w;
        Bs[lc+0][lr] = b4.x; Bs[lc+1][lr] = b4.y; Bs[lc+2][lr] = b4.z; Bs[lc+3][lr] = b4.w;
        __syncthreads();
        #pragma unroll
        for (int kk = 0; kk < 16; ++kk) {
            const float4 av = *(const float4*)&As[kk][ty << 2];
            const float4 bv = *(const float4*)&Bs[kk][tx << 2];
            acc[0][0] = fmaf(av.x, bv.x, acc[0][0]);
            acc[0][1] = fmaf(av.x, bv.y, acc[0][1]);
            acc[0][2] = fmaf(av.x, bv.z, acc[0][2]);
            acc[0][3] = fmaf(av.x, bv.w, acc[0][3]);
            acc[1][0] = fmaf(av.y, bv.x, acc[1][0]);
            acc[1][1] = fmaf(av.y, bv.y, acc[1][1]);
            acc[1][2] = fmaf(av.y, bv.z, acc[1][2]);
            acc[1][3] = fmaf(av.y, bv.w, acc[1][3]);
            acc[2][0] = fmaf(av.z, bv.x, acc[2][0]);
            acc[2][1] = fmaf(av.z, bv.y, acc[2][1]);
            acc[2][2] = fmaf(av.z, bv.z, acc[2][2]);
            acc[2][3] = fmaf(av.z, bv.w, acc[2][3]);
            acc[3][0] = fmaf(av.w, bv.x, acc[3][0]);
            acc[3][1] = fmaf(av.w, bv.y, acc[3][1]);
            acc[3][2] = fmaf(av.w, bv.z, acc[3][2]);
            acc[3][3] = fmaf(av.w, bv.w, acc[3][3]);
        }
    }
    const int n_ctx = n_ctx_p[0];
    const float ts = trust_scale[0];
    #pragma unroll
    for (int i = 0; i < 4; ++i) {
        const int r = row0 + (ty << 2) + i;
        const int c = col0 + (tx << 2);
        float4 o;
        o.x = acc[i][0] + bias[c+0];
        o.y = acc[i][1] + bias[c+1];
        o.z = acc[i][2] + bias[c+2];
        o.w = acc[i][3] + bias[c+3];
        if (mode == 1) {
            if (c < D_) {                      // q part: fold attention scale
                o.x *= 0.125f; o.y *= 0.125f; o.z *= 0.125f; o.w *= 0.125f;
            } else if (c >= 2*D_) {            // v part: trust gate per token
                const int n = r & (N_ - 1);
                if (n < n_ctx) {
                    const float g = 1.f / (1.f + __expf(-ts * ctx_trust[n]));
                    o.x *= g; o.y *= g; o.z *= g; o.w *= g;
                }
            }
        }
        *(float4*)(C + (size_t)r * Ncol + c) = o;
    }
}

// ---------------------------------------------------------------------------
// Flash-style attention over qkv[B*N, 3D] (q pre-scaled, v pre-gated).
// Block: 256 threads = 16 q-rows of one (b,h). Key chunks of 16 in LDS.
// Lane layout: 16 lanes per q-row; each lane owns 1 key (QK^T) and 4 out dims.
// ---------------------------------------------------------------------------
__global__ __launch_bounds__(256) void attn_kernel(
    const float* __restrict__ qkv,
    const int* __restrict__ mask,       // [N,N], nonzero = masked (-inf)
    const float* __restrict__ ctx_ppr,
    const float* __restrict__ log_ppr_alpha,
    const int* __restrict__ n_ctx_p,
    float* __restrict__ out)            // [B*N, D]
{
    __shared__ __align__(16) float Ks[16][68];
    __shared__ __align__(16) float Vs[16][68];
    const int tid  = threadIdx.x;
    const int lane = tid & 63;
    const int wv   = tid >> 6;
    const int rg   = lane >> 4;           // row subgroup within wave
    const int ks   = lane & 15;           // key sub-lane / out-dim group
    const int row_in_block = (wv << 2) | rg;
    const int bh = blockIdx.y;
    const int b  = bh >> 4;
    const int h  = bh & 15;
    const int nq = (blockIdx.x << 4) + row_in_block;
    const int n_ctx   = n_ctx_p[0];
    const float alpha = log_ppr_alpha[0];

    float qreg[64];
    {
        const float* qp = qkv + (size_t)(b * N_ + nq) * TD_ + h * HD_;
        #pragma unroll
        for (int d4 = 0; d4 < 16; ++d4) {
            const float4 t = *(const float4*)(qp + (d4 << 2));
            qreg[(d4<<2)+0] = t.x; qreg[(d4<<2)+1] = t.y;
            qreg[(d4<<2)+2] = t.z; qreg[(d4<<2)+3] = t.w;
        }
    }
    float acc4[4] = {0.f, 0.f, 0.f, 0.f};
    float mrun = -1e30f, lrun = 0.f;     // finite init: avoids inf-inf NaN
    const int* mrow = mask + (size_t)nq * N_;
    const int srow = tid >> 4;            // staging: 16 rows x 16 float4
    const int scol = (tid & 15) << 2;
    const float* kbase = qkv + (size_t)(b * N_) * TD_ + D_ + h * HD_;

    for (int c0 = 0; c0 < N_; c0 += 16) {
        const float* kp = kbase + (size_t)(c0 + srow) * TD_ + scol;
        const float4 k4 = *(const float4*)kp;
        const float4 v4 = *(const float4*)(kp + D_);
        __syncthreads();
        *(float4*)&Ks[srow][scol] = k4;
        *(float4*)&Vs[srow][scol] = v4;
        __syncthreads();

        const int kk = c0 + ks;
        float dot = 0.f;
        #pragma unroll
        for (int d4 = 0; d4 < 16; ++d4) {
            const float4 kv = *(const float4*)&Ks[ks][d4 << 2];
            dot = fmaf(qreg[(d4<<2)+0], kv.x, dot);
            dot = fmaf(qreg[(d4<<2)+1], kv.y, dot);
            dot = fmaf(qreg[(d4<<2)+2], kv.z, dot);
            dot = fmaf(qreg[(d4<<2)+3], kv.w, dot);
        }
        float bias = 0.f;
        if (kk < n_ctx) bias = alpha * __logf(fmaxf(ctx_ppr[kk], 1e-8f));
        float s = dot + bias;                 // q already carries 1/sqrt(HD)
        if (mrow[kk] != 0) s = -INFINITY;

        float cmax = s;
        cmax = fmaxf(cmax, __shfl_xor(cmax, 1));
        cmax = fmaxf(cmax, __shfl_xor(cmax, 2));
        cmax = fmaxf(cmax, __shfl_xor(cmax, 4));
        cmax = fmaxf(cmax, __shfl_xor(cmax, 8));
        const float mnew = fmaxf(mrun, cmax); // uniform across the 16-lane group
        const float sc = __expf(mrun - mnew);
        const float p  = __expf(s - mnew);    // 0 for masked lanes
        mrun = mnew;
        lrun = lrun * sc + p;

        float pt[16];
        #pragma unroll
        for (int t = 0; t < 16; ++t) pt[t] = __shfl(p, (lane & 48) + t, 64);
        acc4[0] *= sc; acc4[1] *= sc; acc4[2] *= sc; acc4[3] *= sc;
        #pragma unroll
        for (int t = 0; t < 16; ++t) {
            const float4 vv = *(const float4*)&Vs[t][ks << 2];
            acc4[0] = fmaf(pt[t], vv.x, acc4[0]);
            acc4[1] = fmaf(pt[t], vv.y, acc4[1]);
            acc4[2] = fmaf(pt[t], vv.z, acc4[2]);
            acc4[3] = fmaf(pt[t], vv.w, acc4[3]);
        }
    }
    float gl = lrun;
    gl += __shfl_xor(gl, 1);
    gl += __shfl_xor(gl, 2);
    gl += __shfl_xor(gl, 4);
    gl += __shfl_xor(gl, 8);
    const float inv = 1.f / gl;
    float4 o;
    o.x = acc4[0] * inv; o.y = acc4[1] * inv;
    o.z = acc4[2] * inv; o.w = acc4[3] * inv;
    *(float4*)(out + (size_t)(b * N_ + nq) * D_ + h * HD_ + (ks << 2)) = o;
}

extern "C" void kernel_launch(void* const* d_in, const int* in_sizes, int n_in,
                              void* d_out, int out_size, void* d_ws, size_t ws_size,
                              hipStream_t stream)
{
    const float* x         = (const float*)d_in[0];
    const float* ctx_ppr   = (const float*)d_in[1];
    const float* ctx_trust = (const float*)d_in[2];
    const int*   n_ctx_p   = (const int*)d_in[3];
    const int*   attn_mask = (const int*)d_in[4];
    const float* W_in      = (const float*)d_in[5];
    const float* b_in      = (const float*)d_in[6];
    const float* W_out     = (const float*)d_in[7];
    const float* b_out     = (const float*)d_in[8];
    const float* log_alpha = (const float*)d_in[9];
    const float* trust_sc  = (const float*)d_in[10];
    float* out = (float*)d_out;

    float* qkv = (float*)d_ws;                        // [4096, 3072] f32 (48 MB)
    float* att = qkv + (size_t)4096 * 3072;           // [4096, 1024] f32 (16 MB)

    // 1) qkv = x @ W_in^T + b_in  (q pre-scaled, v pre-gated)
    hipLaunchKernelGGL(gemm_nt_kernel, dim3(TD_ / 64, (B_ * N_) / 64), dim3(256), 0, stream,
                       x, W_in, b_in, qkv, B_ * N_, TD_, D_, 1,
                       ctx_trust, trust_sc, n_ctx_p);
    // 2) attention
    hipLaunchKernelGGL(attn_kernel, dim3(N_ / 16, B_ * H_), dim3(256), 0, stream,
                       qkv, attn_mask, ctx_ppr, log_alpha, n_ctx_p, att);
    // 3) out = att @ W_out^T + b_out
    hipLaunchKernelGGL(gemm_nt_kernel, dim3(D_ / 64, (B_ * N_) / 64), dim3(256), 0, stream,
                       att, W_out, b_out, out, B_ * N_, D_, D_, 0,
                       ctx_trust, trust_sc, n_ctx_p);
}

// Round 2
// 304.268 us; speedup vs baseline: 5.3571x; 5.3571x over previous
//
#include <hip/hip_runtime.h>
#include <hip/hip_bf16.h>
#include <math.h>

#define B_   2
#define N_   2048
#define D_   1024
#define H_   16
#define TD_  3072

typedef short bf16x8 __attribute__((ext_vector_type(8)));
typedef float f32x4  __attribute__((ext_vector_type(4)));

#define MFMA(a, b, c) __builtin_amdgcn_mfma_f32_16x16x32_bf16(a, b, c, 0, 0, 0)

__device__ __forceinline__ ushort f2bf(float f) {
    union { float f; unsigned u; } v; v.f = f;
    unsigned r = (v.u + 0x7fffu + ((v.u >> 16) & 1u)) >> 16;
    return (ushort)r;
}

__device__ __forceinline__ void async16(const void* g, void* l) {
    __builtin_amdgcn_global_load_lds(
        (const __attribute__((address_space(1))) unsigned*)g,
        (__attribute__((address_space(3))) unsigned*)l, 16, 0, 0);
}

// ---------------------------------------------------------------------------
// Preprocess: f32->bf16 casts of x/W_in/W_out, mask->bitmask, ppr bias row.
// ---------------------------------------------------------------------------
__global__ __launch_bounds__(256) void preprocess(
    const float* __restrict__ x, const float* __restrict__ W_in,
    const float* __restrict__ W_out, const float* __restrict__ ctx_ppr,
    const float* __restrict__ log_alpha, const int* __restrict__ n_ctx_p,
    const int* __restrict__ mask,
    ushort* __restrict__ xb, ushort* __restrict__ wib, ushort* __restrict__ wob,
    float* __restrict__ biasrow, unsigned* __restrict__ maskbits)
{
    const int J0 = 1048576, J1 = 786432, J2 = 262144, JM = 131072, JB = 2048;
    int t = blockIdx.x * 256 + threadIdx.x;
    if (t < J0 + J1 + J2) {
        const float* src; ushort* dst; int i = t;
        if (i < J0)           { src = x;     dst = xb;  }
        else if (i < J0 + J1) { i -= J0;     src = W_in;  dst = wib; }
        else                  { i -= J0 + J1; src = W_out; dst = wob; }
        float4 v = ((const float4*)src)[i];
        ushort4 o;
        o.x = f2bf(v.x); o.y = f2bf(v.y); o.z = f2bf(v.z); o.w = f2bf(v.w);
        ((ushort4*)dst)[i] = o;
    } else if (t < J0 + J1 + J2 + JM) {
        int i = t - (J0 + J1 + J2);
        const int4* m = (const int4*)(mask + (size_t)i * 32);
        unsigned bits = 0u;
        #pragma unroll
        for (int j = 0; j < 8; ++j) {
            int4 w = m[j];
            bits |= (w.x != 0 ? 1u : 0u) << (j * 4 + 0);
            bits |= (w.y != 0 ? 1u : 0u) << (j * 4 + 1);
            bits |= (w.z != 0 ? 1u : 0u) << (j * 4 + 2);
            bits |= (w.w != 0 ? 1u : 0u) << (j * 4 + 3);
        }
        maskbits[i] = bits;
    } else if (t < J0 + J1 + J2 + JM + JB) {
        int k = t - (J0 + J1 + J2 + JM);
        int nc = n_ctx_p[0];
        float bv = 0.f;
        if (k < nc) bv = log_alpha[0] * __logf(fmaxf(ctx_ppr[k], 1e-8f));
        biasrow[k] = bv;
    }
}

// ---------------------------------------------------------------------------
// bf16 MFMA NT GEMM: C[M,Ncol] = A[M,K] @ Bw[Ncol,K]^T + bias.
// 128x128 tile, BK=32, 256 thr (4 waves 2x2 of 64x64), global_load_lds staging,
// XOR-swizzled LDS granules (conflict-free b128 frag reads).
// mode 0: f32 out.  mode 1: bf16 qkv out with q*0.125, v*sigmoid-gate.
// ---------------------------------------------------------------------------
__global__ __launch_bounds__(256) void gemm_bt(
    const ushort* __restrict__ A, const ushort* __restrict__ Bw,
    const float* __restrict__ bias, void* __restrict__ Cout,
    int Ncol, int K, int mode,
    const float* __restrict__ ctx_trust, const float* __restrict__ trust_scale,
    const int* __restrict__ n_ctx_p)
{
    __shared__ ushort tA[128 * 32];
    __shared__ ushort tB[128 * 32];
    const int tid = threadIdx.x;
    const int lane = tid & 63, wv = tid >> 6;
    const int ln = lane & 15, kg = lane >> 4;
    const int rh = wv >> 1, ch = wv & 1;
    const int row0 = blockIdx.y * 128, col0 = blockIdx.x * 128;

    int offA[4], offB[4];
    #pragma unroll
    for (int i = 0; i < 4; ++i) {
        int ra = rh * 64 + i * 16 + ln;
        offA[i] = ra * 32 + ((kg ^ ((ra >> 1) & 3)) << 3);
        int rb = ch * 64 + i * 16 + ln;
        offB[i] = rb * 32 + ((kg ^ ((rb >> 1) & 3)) << 3);
    }
    f32x4 acc[4][4];
    #pragma unroll
    for (int i = 0; i < 4; ++i)
        #pragma unroll
        for (int j = 0; j < 4; ++j) acc[i][j] = (f32x4){0.f, 0.f, 0.f, 0.f};

    for (int kt = 0; kt < K; kt += 32) {
        __syncthreads();
        #pragma unroll
        for (int r2 = 0; r2 < 2; ++r2) {
            int g = r2 * 256 + tid;
            int row = g >> 2;
            int srck = ((g & 3) ^ ((row >> 1) & 3)) << 3;
            async16(A  + (size_t)(row0 + row) * K + kt + srck, &tA[g * 8]);
            async16(Bw + (size_t)(col0 + row) * K + kt + srck, &tB[g * 8]);
        }
        __syncthreads();
        bf16x8 af[4], bfr[4];
        #pragma unroll
        for (int i = 0; i < 4; ++i) af[i]  = *(const bf16x8*)&tA[offA[i]];
        #pragma unroll
        for (int i = 0; i < 4; ++i) bfr[i] = *(const bf16x8*)&tB[offB[i]];
        #pragma unroll
        for (int mt = 0; mt < 4; ++mt)
            #pragma unroll
            for (int nt = 0; nt < 4; ++nt)
                acc[mt][nt] = MFMA(af[mt], bfr[nt], acc[mt][nt]);
    }

    const int nctx = n_ctx_p[0];
    const float ts = trust_scale[0];
    #pragma unroll
    for (int nt = 0; nt < 4; ++nt) {
        int col = col0 + ch * 64 + nt * 16 + ln;
        float bv = bias[col];
        #pragma unroll
        for (int mt = 0; mt < 4; ++mt) {
            int rbase = row0 + rh * 64 + mt * 16 + kg * 4;
            f32x4 a = acc[mt][nt];
            #pragma unroll
            for (int reg = 0; reg < 4; ++reg) {
                int r = rbase + reg;
                float v = a[reg] + bv;
                if (mode == 1) {
                    if (col < D_) v *= 0.125f;
                    else if (col >= 2 * D_) {
                        int n = r & (N_ - 1);
                        if (n < nctx) {
                            float g = 1.f / (1.f + __expf(-ts * ctx_trust[n]));
                            v *= g;
                        }
                    }
                    ((ushort*)Cout)[(size_t)r * TD_ + col] = f2bf(v);
                } else {
                    ((float*)Cout)[(size_t)r * Ncol + col] = v;
                }
            }
        }
    }
}

// ---------------------------------------------------------------------------
// Flash attention, bf16 MFMA. Block = 4 waves x 32 q-rows = 128 q of one (b,h).
// S^T = K·Q^T  (softmax stats per-lane scalar, q = lane&15)
// out^T = V^T·P^T  (A = transposed V tile, B = P[q][key] -> b128 reads)
// K async double-buffered; V register-prefetched one chunk ahead.
// ---------------------------------------------------------------------------
#define PSTR 72
__global__ __launch_bounds__(256) void attn(
    const ushort* __restrict__ qkv, const unsigned* __restrict__ maskbits,
    const float* __restrict__ biasrow, ushort* __restrict__ attb)
{
    __shared__ ushort Kt[2][64 * 64];
    __shared__ ushort Vt[64 * PSTR];
    __shared__ ushort Pq[4][2][16 * PSTR];
    const int tid = threadIdx.x;
    const int lane = tid & 63, wv = tid >> 6;
    const int ln = lane & 15, kg = lane >> 4;
    const int b = blockIdx.y >> 4, h = blockIdx.y & 15;
    const int q0 = blockIdx.x * 128 + wv * 32;

    bf16x8 qf[2][2];
    #pragma unroll
    for (int qh = 0; qh < 2; ++qh) {
        const ushort* qp = qkv + ((size_t)(b * N_) + q0 + qh * 16 + ln) * TD_ + h * 64 + kg * 8;
        qf[qh][0] = *(const bf16x8*)qp;
        qf[qh][1] = *(const bf16x8*)(qp + 32);
    }
    f32x4 o[2][4];
    #pragma unroll
    for (int i = 0; i < 2; ++i)
        #pragma unroll
        for (int j = 0; j < 4; ++j) o[i][j] = (f32x4){0.f, 0.f, 0.f, 0.f};
    float mrun[2] = {-1e30f, -1e30f}, lrun[2] = {0.f, 0.f};

    const int vk0 = (tid & 15) * 4, vh0 = (tid >> 4) * 4;
    const size_t kvrow = (size_t)(b * N_) * TD_ + h * 64;

    ushort4 vld[4];
    #pragma unroll
    for (int i = 0; i < 4; ++i)
        vld[i] = *(const ushort4*)(qkv + kvrow + (size_t)(vk0 + i) * TD_ + 2 * D_ + vh0);

    for (int ci = 0; ci < 32; ++ci) {
        const int c0 = ci * 64;
        __syncthreads();
        // transpose-write V chunk ci
        #pragma unroll
        for (int j = 0; j < 4; ++j) {
            ushort4 w;
            w.x = ((const ushort*)&vld[0])[j];
            w.y = ((const ushort*)&vld[1])[j];
            w.z = ((const ushort*)&vld[2])[j];
            w.w = ((const ushort*)&vld[3])[j];
            *(ushort4*)&Vt[(vh0 + j) * PSTR + vk0] = w;
        }
        if (ci == 0) {
            #pragma unroll
            for (int r2 = 0; r2 < 2; ++r2) {
                int g = r2 * 256 + tid;
                int key = g >> 3;
                int srck = ((g & 7) ^ (key & 7)) << 3;
                async16(qkv + kvrow + (size_t)(c0 + key) * TD_ + D_ + srck, &Kt[0][g * 8]);
            }
        }
        __syncthreads();
        // prefetch next chunk (K -> other Kt buffer, V -> regs)
        if (ci < 31) {
            #pragma unroll
            for (int r2 = 0; r2 < 2; ++r2) {
                int g = r2 * 256 + tid;
                int key = g >> 3;
                int srck = ((g & 7) ^ (key & 7)) << 3;
                async16(qkv + kvrow + (size_t)(c0 + 64 + key) * TD_ + D_ + srck,
                        &Kt[(ci + 1) & 1][g * 8]);
            }
            #pragma unroll
            for (int i = 0; i < 4; ++i)
                vld[i] = *(const ushort4*)(qkv + kvrow + (size_t)(c0 + 64 + vk0 + i) * TD_ + 2 * D_ + vh0);
        }
        const ushort* KT = Kt[ci & 1];

        f32x4 bias4[4];
        #pragma unroll
        for (int t = 0; t < 4; ++t)
            bias4[t] = *(const f32x4*)&biasrow[c0 + t * 16 + kg * 4];

        #pragma unroll
        for (int qh = 0; qh < 2; ++qh) {
            int q = q0 + qh * 16 + ln;
            unsigned mw0 = maskbits[(size_t)q * 64 + ci * 2];
            unsigned mw1 = maskbits[(size_t)q * 64 + ci * 2 + 1];
            f32x4 s[4];
            #pragma unroll
            for (int t = 0; t < 4; ++t) s[t] = (f32x4){0.f, 0.f, 0.f, 0.f};
            #pragma unroll
            for (int t = 0; t < 4; ++t) {
                int key = t * 16 + ln;
                int swk = key & 7;
                bf16x8 k0f = *(const bf16x8*)&KT[key * 64 + ((kg) ^ swk) * 8];
                bf16x8 k1f = *(const bf16x8*)&KT[key * 64 + ((4 + kg) ^ swk) * 8];
                s[t] = MFMA(k0f, qf[qh][0], s[t]);
                s[t] = MFMA(k1f, qf[qh][1], s[t]);
            }
            float sv[4][4];
            float vmax = -1e30f;
            #pragma unroll
            for (int t = 0; t < 4; ++t) {
                unsigned w = (t < 2) ? mw0 : mw1;
                #pragma unroll
                for (int reg = 0; reg < 4; ++reg) {
                    int kl = t * 16 + kg * 4 + reg;
                    float v = s[t][reg] + bias4[t][reg];
                    if ((w >> (kl & 31)) & 1u) v = -1e30f;
                    sv[t][reg] = v;
                    vmax = fmaxf(vmax, v);
                }
            }
            vmax = fmaxf(vmax, __shfl_xor(vmax, 16));
            vmax = fmaxf(vmax, __shfl_xor(vmax, 32));
            float mnew = fmaxf(mrun[qh], vmax);
            float scl = __expf(mrun[qh] - mnew);
            mrun[qh] = mnew;
            float lsum = 0.f;
            #pragma unroll
            for (int t = 0; t < 4; ++t) {
                float p0 = sv[t][0] <= -1e29f ? 0.f : __expf(sv[t][0] - mnew);
                float p1 = sv[t][1] <= -1e29f ? 0.f : __expf(sv[t][1] - mnew);
                float p2 = sv[t][2] <= -1e29f ? 0.f : __expf(sv[t][2] - mnew);
                float p3 = sv[t][3] <= -1e29f ? 0.f : __expf(sv[t][3] - mnew);
                lsum += p0 + p1 + p2 + p3;
                ushort4 pk;
                pk.x = f2bf(p0); pk.y = f2bf(p1); pk.z = f2bf(p2); pk.w = f2bf(p3);
                *(ushort4*)&Pq[wv][qh][ln * PSTR + t * 16 + kg * 4] = pk;
            }
            lsum += __shfl_xor(lsum, 16);
            lsum += __shfl_xor(lsum, 32);
            lrun[qh] = lrun[qh] * scl + lsum;
            #pragma unroll
            for (int ht = 0; ht < 4; ++ht) o[qh][ht] *= scl;
        }
        // PV: out^T += V^T · P^T
        #pragma unroll
        for (int kc = 0; kc < 2; ++kc) {
            bf16x8 pf0 = *(const bf16x8*)&Pq[wv][0][ln * PSTR + kc * 32 + kg * 8];
            bf16x8 pf1 = *(const bf16x8*)&Pq[wv][1][ln * PSTR + kc * 32 + kg * 8];
            #pragma unroll
            for (int ht = 0; ht < 4; ++ht) {
                bf16x8 vf = *(const bf16x8*)&Vt[(ht * 16 + ln) * PSTR + kc * 32 + kg * 8];
                o[0][ht] = MFMA(vf, pf0, o[0][ht]);
                o[1][ht] = MFMA(vf, pf1, o[1][ht]);
            }
        }
    }
    #pragma unroll
    for (int qh = 0; qh < 2; ++qh) {
        float inv = 1.f / lrun[qh];
        int q = q0 + qh * 16 + ln;
        ushort* op = attb + ((size_t)(b * N_) + q) * D_ + h * 64;
        #pragma unroll
        for (int ht = 0; ht < 4; ++ht)
            #pragma unroll
            for (int reg = 0; reg < 4; ++reg)
                op[ht * 16 + kg * 4 + reg] = f2bf(o[qh][ht][reg] * inv);
    }
}

extern "C" void kernel_launch(void* const* d_in, const int* in_sizes, int n_in,
                              void* d_out, int out_size, void* d_ws, size_t ws_size,
                              hipStream_t stream)
{
    const float* x         = (const float*)d_in[0];
    const float* ctx_ppr   = (const float*)d_in[1];
    const float* ctx_trust = (const float*)d_in[2];
    const int*   n_ctx_p   = (const int*)d_in[3];
    const int*   attn_mask = (const int*)d_in[4];
    const float* W_in      = (const float*)d_in[5];
    const float* b_in      = (const float*)d_in[6];
    const float* W_out     = (const float*)d_in[7];
    const float* b_out     = (const float*)d_in[8];
    const float* log_alpha = (const float*)d_in[9];
    const float* trust_sc  = (const float*)d_in[10];
    float* out = (float*)d_out;

    char* ws = (char*)d_ws;
    ushort*   xb       = (ushort*)ws;                    ws += (size_t)4096 * 1024 * 2;   // 8 MB
    ushort*   wib      = (ushort*)ws;                    ws += (size_t)3072 * 1024 * 2;   // 6 MB
    ushort*   wob      = (ushort*)ws;                    ws += (size_t)1024 * 1024 * 2;   // 2 MB
    ushort*   qkvb     = (ushort*)ws;                    ws += (size_t)4096 * 3072 * 2;   // 24 MB
    ushort*   attbuf   = (ushort*)ws;                    ws += (size_t)4096 * 1024 * 2;   // 8 MB
    float*    biasrow  = (float*)ws;                     ws += 2048 * 4;
    unsigned* maskbits = (unsigned*)ws;                  ws += (size_t)2048 * 64 * 4;     // 512 KB

    hipLaunchKernelGGL(preprocess, dim3(8712), dim3(256), 0, stream,
                       x, W_in, W_out, ctx_ppr, log_alpha, n_ctx_p, attn_mask,
                       xb, wib, wob, biasrow, maskbits);

    hipLaunchKernelGGL(gemm_bt, dim3(24, 32), dim3(256), 0, stream,
                       xb, wib, b_in, (void*)qkvb, TD_, 1024, 1,
                       ctx_trust, trust_sc, n_ctx_p);

    hipLaunchKernelGGL(attn, dim3(16, 32), dim3(256), 0, stream,
                       qkvb, maskbits, biasrow, attbuf);

    hipLaunchKernelGGL(gemm_bt, dim3(8, 32), dim3(256), 0, stream,
                       attbuf, wob, b_out, (void*)out, 1024, 1024, 0,
                       ctx_trust, trust_sc, n_ctx_p);
}

// Round 4
// 268.450 us; speedup vs baseline: 6.0719x; 1.1334x over previous
//
#include <hip/hip_runtime.h>
#include <hip/hip_bf16.h>
#include <math.h>

#define B_   2
#define N_   2048
#define D_   1024
#define H_   16
#define TD_  3072
#define LOG2E 1.44269504088896340736f
#define SCALE_Q (0.125f * LOG2E)

typedef short  bf16x8 __attribute__((ext_vector_type(8)));
typedef _Float16 f16x8 __attribute__((ext_vector_type(8)));
typedef float  f32x4  __attribute__((ext_vector_type(4)));
typedef float  f32x16 __attribute__((ext_vector_type(16)));

#define MFMA16(a, b, c)   __builtin_amdgcn_mfma_f32_16x16x32_bf16(a, b, c, 0, 0, 0)
#define MFMA32B(a, b, c)  __builtin_amdgcn_mfma_f32_32x32x16_bf16(a, b, c, 0, 0, 0)
#define MFMA32H(a, b, c)  __builtin_amdgcn_mfma_f32_32x32x16_f16(a, b, c, 0, 0, 0)

__device__ __forceinline__ ushort f2bf(float f) {
    union { float f; unsigned u; } v; v.f = f;
    unsigned r = (v.u + 0x7fffu + ((v.u >> 16) & 1u)) >> 16;
    return (ushort)r;
}
__device__ __forceinline__ unsigned pkrtz(float a, float b) {
    typedef __fp16 h2 __attribute__((ext_vector_type(2)));
    union { h2 h; unsigned u; } c;
    c.h = __builtin_amdgcn_cvt_pkrtz(a, b);
    return c.u;
}
__device__ __forceinline__ void async16(const void* g, void* l) {
    __builtin_amdgcn_global_load_lds(
        (const __attribute__((address_space(1))) unsigned*)g,
        (__attribute__((address_space(3))) unsigned*)l, 16, 0, 0);
}

// ---------------------------------------------------------------------------
// Preprocess: bf16 casts, mask->bitmask, log2-domain ppr bias row.
// ---------------------------------------------------------------------------
__global__ __launch_bounds__(256) void preprocess(
    const float* __restrict__ x, const float* __restrict__ W_in,
    const float* __restrict__ W_out, const float* __restrict__ ctx_ppr,
    const float* __restrict__ log_alpha, const int* __restrict__ n_ctx_p,
    const int* __restrict__ mask,
    ushort* __restrict__ xb, ushort* __restrict__ wib, ushort* __restrict__ wob,
    float* __restrict__ biasrow, unsigned* __restrict__ maskbits)
{
    const int J0 = 1048576, J1 = 786432, J2 = 262144, JM = 131072, JB = 2048;
    int t = blockIdx.x * 256 + threadIdx.x;
    if (t < J0 + J1 + J2) {
        const float* src; ushort* dst; int i = t;
        if (i < J0)           { src = x;      dst = xb;  }
        else if (i < J0 + J1) { i -= J0;      src = W_in;  dst = wib; }
        else                  { i -= J0 + J1; src = W_out; dst = wob; }
        float4 v = ((const float4*)src)[i];
        ushort4 o;
        o.x = f2bf(v.x); o.y = f2bf(v.y); o.z = f2bf(v.z); o.w = f2bf(v.w);
        ((ushort4*)dst)[i] = o;
    } else if (t < J0 + J1 + J2 + JM) {
        int i = t - (J0 + J1 + J2);
        const int4* m = (const int4*)(mask + (size_t)i * 32);
        unsigned bits = 0u;
        #pragma unroll
        for (int j = 0; j < 8; ++j) {
            int4 w = m[j];
            bits |= (w.x != 0 ? 1u : 0u) << (j * 4 + 0);
            bits |= (w.y != 0 ? 1u : 0u) << (j * 4 + 1);
            bits |= (w.z != 0 ? 1u : 0u) << (j * 4 + 2);
            bits |= (w.w != 0 ? 1u : 0u) << (j * 4 + 3);
        }
        maskbits[i] = bits;
    } else if (t < J0 + J1 + J2 + JM + JB) {
        int k = t - (J0 + J1 + J2 + JM);
        int nc = n_ctx_p[0];
        float bv = 0.f;
        if (k < nc) bv = log_alpha[0] * __log2f(fmaxf(ctx_ppr[k], 1e-8f));
        biasrow[k] = bv;   // log2-domain bias
    }
}

// ---------------------------------------------------------------------------
// bf16 MFMA NT GEMM, 128xBCOL tile, BK=32, 4 waves.
// MODE 0: f32 out (+bias).  MODE 1: qkv epilogue — q*SCALE_Q->bf16 qk buffer,
// k->bf16 qk buffer, v*trust-gate->f16 V^T buffer [bh*64+dim][2048 tokens].
// ---------------------------------------------------------------------------
template<int BCOL, int MODE>
__global__ __launch_bounds__(256) void gemm_bt(
    const ushort* __restrict__ A, const ushort* __restrict__ Bw,
    const float* __restrict__ bias, float* __restrict__ Cout,
    ushort* __restrict__ qkout, _Float16* __restrict__ vTout,
    int Ncol, int K,
    const float* __restrict__ ctx_trust, const float* __restrict__ trust_scale,
    const int* __restrict__ n_ctx_p)
{
    constexpr int NT = BCOL / 32;      // col 16-tiles per wave
    __shared__ ushort tA[128 * 32];
    __shared__ ushort tB[BCOL * 32];
    const int tid = threadIdx.x;
    const int lane = tid & 63, wv = tid >> 6;
    const int ln = lane & 15, kg = lane >> 4;
    const int rh = wv >> 1, ch = wv & 1;
    const int row0 = blockIdx.y * 128, col0 = blockIdx.x * BCOL;

    int offA[4], offB[NT];
    #pragma unroll
    for (int i = 0; i < 4; ++i) {
        int ra = rh * 64 + i * 16 + ln;
        offA[i] = ra * 32 + ((kg ^ ((ra >> 1) & 3)) << 3);
    }
    #pragma unroll
    for (int i = 0; i < NT; ++i) {
        int rb = ch * (BCOL / 2) + i * 16 + ln;
        offB[i] = rb * 32 + ((kg ^ ((rb >> 1) & 3)) << 3);
    }
    f32x4 acc[4][NT];
    #pragma unroll
    for (int i = 0; i < 4; ++i)
        #pragma unroll
        for (int j = 0; j < NT; ++j) acc[i][j] = (f32x4){0.f, 0.f, 0.f, 0.f};

    for (int kt = 0; kt < K; kt += 32) {
        __syncthreads();
        #pragma unroll
        for (int r2 = 0; r2 < 2; ++r2) {
            int g = r2 * 256 + tid;
            int row = g >> 2;
            int srck = ((g & 3) ^ ((row >> 1) & 3)) << 3;
            async16(A + (size_t)(row0 + row) * K + kt + srck, &tA[g * 8]);
        }
        #pragma unroll
        for (int r2 = 0; r2 < BCOL / 64; ++r2) {
            int g = r2 * 256 + tid;
            int row = g >> 2;
            int srck = ((g & 3) ^ ((row >> 1) & 3)) << 3;
            async16(Bw + (size_t)(col0 + row) * K + kt + srck, &tB[g * 8]);
        }
        __syncthreads();
        bf16x8 af[4], bfr[NT];
        #pragma unroll
        for (int i = 0; i < 4; ++i)  af[i]  = *(const bf16x8*)&tA[offA[i]];
        #pragma unroll
        for (int i = 0; i < NT; ++i) bfr[i] = *(const bf16x8*)&tB[offB[i]];
        #pragma unroll
        for (int mt = 0; mt < 4; ++mt)
            #pragma unroll
            for (int nt = 0; nt < NT; ++nt)
                acc[mt][nt] = MFMA16(af[mt], bfr[nt], acc[mt][nt]);
    }

    const int nctx = n_ctx_p ? n_ctx_p[0] : 0;
    const float ts = trust_scale ? trust_scale[0] : 0.f;
    #pragma unroll
    for (int nt = 0; nt < NT; ++nt) {
        int col = col0 + ch * (BCOL / 2) + nt * 16 + ln;
        float bv = bias[col];
        #pragma unroll
        for (int mt = 0; mt < 4; ++mt) {
            int rbase = row0 + rh * 64 + mt * 16 + kg * 4;
            f32x4 a = acc[mt][nt];
            if (MODE == 0) {
                #pragma unroll
                for (int reg = 0; reg < 4; ++reg)
                    Cout[(size_t)(rbase + reg) * Ncol + col] = a[reg] + bv;
            } else {
                if (col < D_) {
                    #pragma unroll
                    for (int reg = 0; reg < 4; ++reg)
                        qkout[(size_t)(rbase + reg) * 2048 + col] =
                            f2bf((a[reg] + bv) * SCALE_Q);
                } else if (col < 2 * D_) {
                    #pragma unroll
                    for (int reg = 0; reg < 4; ++reg)
                        qkout[(size_t)(rbase + reg) * 2048 + col] = f2bf(a[reg] + bv);
                } else {
                    int vc = col - 2 * D_;
                    int hh = vc >> 6, dim = vc & 63;
                    int bb = rbase >> 11, nbase = rbase & (N_ - 1);
                    ushort4 o;
                    #pragma unroll
                    for (int reg = 0; reg < 4; ++reg) {
                        float v = a[reg] + bv;
                        int n = nbase + reg;
                        if (n < nctx) {
                            float g = 1.f / (1.f + __expf(-ts * ctx_trust[n]));
                            v *= g;
                        }
                        _Float16 hv = (_Float16)v;
                        ((ushort*)&o)[reg] = *(ushort*)&hv;
                    }
                    *(ushort4*)&vTout[((size_t)(bb * 16 + hh) * 64 + dim) * 2048 + nbase] = o;
                }
            }
        }
    }
}

// ---------------------------------------------------------------------------
// Flash attention, 32x32 MFMA, max-less log2-domain softmax.
// Block = 4 waves x 32 q = 128 q of one (b,h). 64-key chunks, K/V async
// double-buffered via global_load_lds, P kept in registers (shfl transform).
// ---------------------------------------------------------------------------
__global__ __launch_bounds__(256) void attn(
    const ushort* __restrict__ qkb,      // [4096][2048] bf16: q | k
    const _Float16* __restrict__ vT,     // [32*64][2048] f16  (b,h,dim) x token
    const unsigned* __restrict__ maskbits,
    const float* __restrict__ biasrow,   // log2-domain, 0 beyond n_ctx
    const int* __restrict__ n_ctx_p,
    ushort* __restrict__ attb)           // [4096][1024] bf16
{
    __shared__ ushort   Kt[2][64 * 64];
    __shared__ _Float16 Vt[2][64 * 64];
    const int tid = threadIdx.x;
    const int lane = tid & 63, wv = tid >> 6;
    const int q31 = lane & 31, hi = lane >> 5;
    const int b = blockIdx.y >> 4, h = blockIdx.y & 15;
    const int q0w = blockIdx.x * 128 + wv * 32;
    const int nctx = n_ctx_p[0];

    // Q B-fragments: B[k=dim][n=q], lane n=q31, k = hi*8+j per kstep
    bf16x8 qf[4];
    {
        const ushort* qrow = qkb + (size_t)(b * N_ + q0w + q31) * 2048 + h * 64;
        #pragma unroll
        for (int ks = 0; ks < 4; ++ks)
            qf[ks] = *(const bf16x8*)(qrow + ks * 16 + hi * 8);
    }
    const size_t kgbase = (size_t)(b * N_) * 2048 + 1024 + h * 64;
    const _Float16* vbase = vT + (size_t)((b * 16 + h) * 64) * 2048;

    f32x16 O[2];
    O[0] = (f32x16)(0.f); O[1] = (f32x16)(0.f);
    float lrun = 0.f;

    // stage chunk 0
    {
        #pragma unroll
        for (int r2 = 0; r2 < 2; ++r2) {
            int g = r2 * 256 + tid; int row = g >> 3; int sg = (g & 7) ^ (row & 7);
            async16(qkb + kgbase + (size_t)row * 2048 + sg * 8, &Kt[0][g * 8]);
        }
        #pragma unroll
        for (int r2 = 0; r2 < 2; ++r2) {
            int g = r2 * 256 + tid; int row = g >> 3; int sg = (g & 7) ^ (row & 7);
            async16(vbase + (size_t)row * 2048 + sg * 8, &Vt[0][g * 8]);
        }
    }

    const int swz = q31 & 7;
    for (int ci = 0; ci < 32; ++ci) {
        const int c0 = ci * 64;
        __syncthreads();   // drains this wave's async issues; all waves aligned
        if (ci < 31) {
            const int c1 = c0 + 64, nb = (ci + 1) & 1;
            #pragma unroll
            for (int r2 = 0; r2 < 2; ++r2) {
                int g = r2 * 256 + tid; int row = g >> 3; int sg = (g & 7) ^ (row & 7);
                async16(qkb + kgbase + (size_t)(c1 + row) * 2048 + sg * 8, &Kt[nb][g * 8]);
            }
            #pragma unroll
            for (int r2 = 0; r2 < 2; ++r2) {
                int g = r2 * 256 + tid; int row = g >> 3; int sg = (g & 7) ^ (row & 7);
                async16(vbase + (size_t)row * 2048 + c1 + sg * 8, &Vt[nb][g * 8]);
            }
        }
        const ushort*   KT = Kt[ci & 1];
        const _Float16* VT = Vt[ci & 1];

        // ---- S^T = K · Q^T  (two 32-key tiles) ----
        f32x16 S[2];
        S[0] = (f32x16)(0.f); S[1] = (f32x16)(0.f);
        #pragma unroll
        for (int t = 0; t < 2; ++t) {
            const int rbase = (t * 32 + q31) * 64;
            #pragma unroll
            for (int ks = 0; ks < 4; ++ks) {
                bf16x8 kf = *(const bf16x8*)&KT[rbase + (((ks * 2 + hi) ^ swz) << 3)];
                S[t] = MFMA32B(kf, qf[ks], S[t]);
            }
        }

        // ---- softmax (no max; fixed -4 offset in log2 domain) ----
        uint2 mw = *(const uint2*)&maskbits[(size_t)(q0w + q31) * 64 + ci * 2];
        unsigned msh[2] = { mw.x >> (hi * 4), mw.y >> (hi * 4) };
        unsigned pk[2][8];
        float lsum = 0.f;
        const bool has_bias = (c0 < nctx);
        #pragma unroll
        for (int t = 0; t < 2; ++t) {
            float p[16];
            #pragma unroll
            for (int g = 0; g < 4; ++g) {
                f32x4 bb = (f32x4){0.f, 0.f, 0.f, 0.f};
                if (has_bias)
                    bb = *(const f32x4*)&biasrow[c0 + t * 32 + g * 8 + hi * 4];
                #pragma unroll
                for (int r = 0; r < 4; ++r) {
                    const int reg = g * 4 + r;
                    const int br = r + 8 * g;          // bit pos after >> 4*hi
                    float s = S[t][reg] + bb[r] - 4.f;
                    s = ((msh[t] >> br) & 1u) ? -1e30f : s;
                    p[reg] = __builtin_exp2f(s);
                }
            }
            float l0 = (p[0] + p[1]) + (p[2] + p[3]);
            float l1 = (p[4] + p[5]) + (p[6] + p[7]);
            float l2 = (p[8] + p[9]) + (p[10] + p[11]);
            float l3 = (p[12] + p[13]) + (p[14] + p[15]);
            lsum += (l0 + l1) + (l2 + l3);
            #pragma unroll
            for (int i = 0; i < 8; ++i)
                pk[t][i] = pkrtz(p[2 * i], p[2 * i + 1]);
        }
        lrun += lsum;

        // ---- PV: out^T += V^T · P^T ----
        #pragma unroll
        for (int ks = 0; ks < 4; ++ks) {
            const int t = ks >> 1, lo4 = (ks & 1) * 4;
            unsigned u0 = pk[t][lo4 + 0], u1 = pk[t][lo4 + 1];
            unsigned u2 = pk[t][lo4 + 2], u3 = pk[t][lo4 + 3];
            unsigned own0 = hi ? u2 : u0, own1 = hi ? u3 : u1;
            unsigned snd0 = hi ? u0 : u2, snd1 = hi ? u1 : u3;
            unsigned rv0 = (unsigned)__shfl_xor((int)snd0, 32);
            unsigned rv1 = (unsigned)__shfl_xor((int)snd1, 32);
            union { f16x8 v; unsigned u[4]; } frag;
            frag.u[0] = hi ? rv0 : own0;
            frag.u[1] = hi ? rv1 : own1;
            frag.u[2] = hi ? own0 : rv0;
            frag.u[3] = hi ? own1 : rv1;
            #pragma unroll
            for (int t2 = 0; t2 < 2; ++t2) {
                const int vb = (t2 * 32 + q31) * 64;
                union { f16x8 v; int4 i; } vf;
                vf.i = *(const int4*)&VT[vb + (((ks * 2 + hi) ^ swz) << 3)];
                O[t2] = MFMA32H(vf.v, frag.v, O[t2]);
            }
        }
    }

    // ---- epilogue: normalize, bf16 store ----
    float l = lrun + __shfl_xor(lrun, 32);
    float inv = 1.f / l;
    ushort* orow = attb + (size_t)(b * N_ + q0w + q31) * 1024 + h * 64;
    #pragma unroll
    for (int t = 0; t < 2; ++t)
        #pragma unroll
        for (int g = 0; g < 4; ++g) {
            ushort4 o;
            #pragma unroll
            for (int r = 0; r < 4; ++r)
                ((ushort*)&o)[r] = f2bf(O[t][g * 4 + r] * inv);
            *(ushort4*)&orow[t * 32 + g * 8 + hi * 4] = o;
        }
}

extern "C" void kernel_launch(void* const* d_in, const int* in_sizes, int n_in,
                              void* d_out, int out_size, void* d_ws, size_t ws_size,
                              hipStream_t stream)
{
    const float* x         = (const float*)d_in[0];
    const float* ctx_ppr   = (const float*)d_in[1];
    const float* ctx_trust = (const float*)d_in[2];
    const int*   n_ctx_p   = (const int*)d_in[3];
    const int*   attn_mask = (const int*)d_in[4];
    const float* W_in      = (const float*)d_in[5];
    const float* b_in      = (const float*)d_in[6];
    const float* W_out     = (const float*)d_in[7];
    const float* b_out     = (const float*)d_in[8];
    const float* log_alpha = (const float*)d_in[9];
    const float* trust_sc  = (const float*)d_in[10];
    float* out = (float*)d_out;

    char* ws = (char*)d_ws;
    ushort*    xb       = (ushort*)ws;    ws += (size_t)4096 * 1024 * 2;   // 8 MB
    ushort*    wib      = (ushort*)ws;    ws += (size_t)3072 * 1024 * 2;   // 6 MB
    ushort*    wob      = (ushort*)ws;    ws += (size_t)1024 * 1024 * 2;   // 2 MB
    ushort*    qkb      = (ushort*)ws;    ws += (size_t)4096 * 2048 * 2;   // 16 MB
    _Float16*  vT       = (_Float16*)ws;  ws += (size_t)2048 * 2048 * 2;   // 8 MB
    ushort*    attbuf   = (ushort*)ws;    ws += (size_t)4096 * 1024 * 2;   // 8 MB
    float*     biasrow  = (float*)ws;     ws += 2048 * 4;
    unsigned*  maskbits = (unsigned*)ws;  ws += (size_t)2048 * 64 * 4;     // 512 KB

    hipLaunchKernelGGL(preprocess, dim3(8712), dim3(256), 0, stream,
                       x, W_in, W_out, ctx_ppr, log_alpha, n_ctx_p, attn_mask,
                       xb, wib, wob, biasrow, maskbits);

    hipLaunchKernelGGL((gemm_bt<128, 1>), dim3(24, 32), dim3(256), 0, stream,
                       xb, wib, b_in, (float*)nullptr, qkb, vT, TD_, 1024,
                       ctx_trust, trust_sc, n_ctx_p);

    hipLaunchKernelGGL(attn, dim3(16, 32), dim3(256), 0, stream,
                       qkb, vT, maskbits, biasrow, n_ctx_p, attbuf);

    hipLaunchKernelGGL((gemm_bt<64, 0>), dim3(16, 32), dim3(256), 0, stream,
                       attbuf, wob, b_out, out, (ushort*)nullptr, (_Float16*)nullptr,
                       1024, 1024, ctx_trust, trust_sc, n_ctx_p);
}